// Round 22
// baseline (605.814 us; speedup 1.0000x reference)
//
#include <hip/hip_runtime.h>

// Problem constants: B=64, T=256, V=4096, H=512
// Inputs: x[B*T] i32, Wxh[V,H] f32, Whh[H,H] f32, bh[H] f32, Wo[H,V] f32, Bo[V] f32
// Output: out[B,T,V] f32 = (scan hs) @ Wo + Bo

typedef __fp16 half2_t __attribute__((ext_vector_type(2)));
typedef __attribute__((ext_vector_type(8))) short short8;   // 8 bf16 (MFMA A/B frag)
typedef __attribute__((ext_vector_type(4))) float f32x4;    // MFMA C/D frag

__device__ __forceinline__ unsigned short f32_to_bf16(float f) {
  unsigned int u = __builtin_bit_cast(unsigned int, f);
  u = (u + 0x7FFFu + ((u >> 16) & 1u)) >> 16;  // RNE
  return (unsigned short)u;
}

__device__ __forceinline__ unsigned int pack_f16x2(float a, float b) {
  half2_t h = __builtin_amdgcn_cvt_pkrtz(a, b);
  return __builtin_bit_cast(unsigned int, h);
}

__device__ __forceinline__ float fdot2_(unsigned int w, unsigned int h, float acc) {
  return __builtin_amdgcn_fdot2(__builtin_bit_cast(half2_t, w),
                                __builtin_bit_cast(half2_t, h), acc, false);
}

__device__ __forceinline__ void glds16(const void* g, void* lds) {
  __builtin_amdgcn_global_load_lds(
      (const __attribute__((address_space(1))) unsigned int*)g,
      (__attribute__((address_space(3))) unsigned int*)lds, 16, 0, 0);
}

// ---------------------------------------------------------------------------
// Prep 1: Whh -> WhhB per-slice LDS image (R15/R17 layout, unchanged). u32
// flat idx = G*4+e, G = ((s*4 + q)*16 + u)*128 + c: f16 pair p = q*64+u*4+e
// of column j = s*128+c  (in-scan chunk kc = q*16+u: wlds[kc*128+c] holds
// pairs [4kc,4kc+4) of column s*128+c). Zeroes hG64 tags every launch.
// ---------------------------------------------------------------------------
__global__ __launch_bounds__(256) void pack_whhB(const float* __restrict__ Whh,
                                                 unsigned int* __restrict__ WhhB,
                                                 unsigned long long* __restrict__ hG64) {
  int idx = blockIdx.x * 256 + threadIdx.x;  // 131072 threads
  int e = idx & 3;
  int G = idx >> 2;
  int c = G & 127;
  int u = (G >> 7) & 15;
  int q = (G >> 11) & 3;
  int s = G >> 13;
  int p = q * 64 + u * 4 + e;   // f16-pair index 0..255
  int j = s * 128 + c;          // column
  float f0 = Whh[(2 * p) * 512 + j];
  float f1 = Whh[(2 * p + 1) * 512 + j];
  WhhB[idx] = pack_f16x2(f0, f1);
  if (idx < 32768) hG64[idx] = 0ull;  // tag 0 != any target t>=1
}

// ---------------------------------------------------------------------------
// Prep 2: Wo [h][v] f32 -> WoT [v][h] bf16
// ---------------------------------------------------------------------------
__global__ __launch_bounds__(256) void transpose_wo(const float* __restrict__ Wo,
                                                    unsigned short* __restrict__ WoT) {
  __shared__ float tile[64][65];
  const int tv = blockIdx.x;   // 0..63  (V/64)
  const int th = blockIdx.y;   // 0..7   (H/64)
  const int tid = threadIdx.x;
  const int c = tid & 63, r4 = tid >> 6;
#pragma unroll
  for (int p = 0; p < 16; ++p) {
    int hl = p * 4 + r4;
    tile[hl][c] = Wo[(size_t)(th * 64 + hl) * 4096 + tv * 64 + c];
  }
  __syncthreads();
#pragma unroll
  for (int p = 0; p < 16; ++p) {
    int vl = p * 4 + r4;
    WoT[(size_t)(tv * 64 + vl) * 512 + th * 64 + c] = f32_to_bf16(tile[c][vl]);
  }
}

// ---------------------------------------------------------------------------
// Recurrence vH: champion (R17/R21) with the pbuf round-trip replaced by a
// cross-lane reduce. Thread mapping TRANSPOSED: c = tid>>2 (column), q =
// tid&3 (k-phase) -> a column's 4 partials live in ADJACENT LANES, so the
// reduce is 2x shfl_xor (no LDS, no barrier) and the pair-pack for the
// tagged store is shfl_down(,4). Step: phase1(own-quarter dots) || poll ->
// barrier -> phase2 -> shfl reduce -> tagged pre-tanh store -> barrier.
// 3 barriers -> 2; ~400-500 cyc off the serialized finalize path. Sync
// protocol byte-identical to R15/R17 (tagged u64, parity buffers, 192
// pollers, tags zeroed per launch).
// ---------------------------------------------------------------------------
#define DOTK(kc_, A) do { \
  const uint4 w_ = wlds[(kc_) * 128 + c]; \
  const uint4 h_ = hbuf[(kc_)]; \
  A = fdot2_(w_.x, h_.x, A); A = fdot2_(w_.y, h_.y, A); \
  A = fdot2_(w_.z, h_.z, A); A = fdot2_(w_.w, h_.w, A); } while (0)

__global__ __launch_bounds__(512) void rnn_scanH(const int* __restrict__ x,
                                                 const float* __restrict__ Wxh,
                                                 const unsigned int* __restrict__ WhhB,
                                                 const float* __restrict__ bh,
                                                 unsigned short* __restrict__ hs,
                                                 unsigned long long* hG64) {
  __shared__ uint4 wlds[8192];   // 128 KB: this block's full weight slice
  __shared__ uint4 hbuf[64];     // 512 h values as f16 pairs
  __shared__ int toks[256];
  const int bid = blockIdx.x;
  const int s = bid & 3;         // column-slice (proven mapping)
  const int b = bid >> 2;        // batch
  const int tid = threadIdx.x;
  const int c = tid >> 2;        // column within slice (0..127)
  const int q = tid & 3;         // k-phase (lane bits 0-1)
  const int s16 = s * 16;
  const uint4* W4 = (const uint4*)WhhB;

  // stage this block's 128 KB weight slice (coalesced, 16 rounds)
#pragma unroll
  for (int it = 0; it < 16; ++it) {
    int L = it * 512 + tid;
    wlds[L] = W4[s * 8192 + L];
  }
  if (tid < 64) hbuf[tid] = make_uint4(0u, 0u, 0u, 0u);  // h0 = 0
  if (tid < 256) toks[tid] = x[b * 256 + tid];
  __syncthreads();

  unsigned int* hb32 = (unsigned int*)hbuf;      // [256] u32 view of h pairs
  const float bhj = bh[s * 128 + c];
  // poll-slot for tid<192: word index within 256, skipping own slice
  const int rslot = (tid < s * 64) ? tid : tid + 64;

  for (int t = 0; t < 256; ++t) {
    const int tok = toks[t];
    // xv prefetch (16 distinct addrs/wave, broadcast within 4-lane groups)
    const float xv = Wxh[(size_t)tok * 512 + s * 128 + c];

    float a0 = 0.f, a1 = 0.f, a2 = 0.f, a3 = 0.f;
    // phase 1: own-quarter chunks (h written locally last step) --
    // overlaps the siblings' store->LLC-visibility window
    DOTK(s16 + 0 + q, a0); DOTK(s16 + 4 + q, a1);
    DOTK(s16 + 8 + q, a2); DOTK(s16 + 12 + q, a3);

    if (t > 0 && tid < 192) {
      // pull 192 remote u-pairs: spin on own tagged word, tanh on receipt
      const unsigned long long* src =
          hG64 + (((size_t)(t & 1)) << 14) + b * 256 + rslot;
      unsigned long long v;
      do {
        v = __hip_atomic_load(src, __ATOMIC_RELAXED, __HIP_MEMORY_SCOPE_AGENT);
      } while ((unsigned)(v >> 32) != (unsigned)t);
      half2_t up = __builtin_bit_cast(half2_t, (unsigned)v);
      hb32[rslot] = pack_f16x2(tanhf((float)up.x), tanhf((float)up.y));
    }
    __syncthreads();  // remote h in LDS for all waves

    // phase 2: the three remote quarters
    {
      int m1 = ((s + 1) & 3) * 16;
      DOTK(m1 + 0 + q, a0); DOTK(m1 + 4 + q, a1);
      DOTK(m1 + 8 + q, a2); DOTK(m1 + 12 + q, a3);
      int m2 = ((s + 2) & 3) * 16;
      DOTK(m2 + 0 + q, a0); DOTK(m2 + 4 + q, a1);
      DOTK(m2 + 8 + q, a2); DOTK(m2 + 12 + q, a3);
      int m3 = ((s + 3) & 3) * 16;
      DOTK(m3 + 0 + q, a0); DOTK(m3 + 4 + q, a1);
      DOTK(m3 + 8 + q, a2); DOTK(m3 + 12 + q, a3);
    }
    // cross-lane k-reduce: q lives in lane bits 0-1
    float asum = (a0 + a1) + (a2 + a3);
    asum += __shfl_xor(asum, 1);
    asum += __shfl_xor(asum, 2);

    const float u1 = xv + asum + bhj;          // valid on all 4 q-lanes
    const float u2 = __shfl_down(u1, 4);       // col c+1's u (lanes c even)
    if ((tid & 7) == 0) {                      // one lane per even column
      const unsigned int up = pack_f16x2(u1, u2);
      __hip_atomic_store(
          hG64 + (((size_t)((t + 1) & 1)) << 14) + b * 256 + 64 * s + (tid >> 3),
          ((unsigned long long)(unsigned)(t + 1) << 32) | up,
          __ATOMIC_RELAXED, __HIP_MEMORY_SCOPE_AGENT);
      // own h from the SAME rounded u (bit-consistent with readers)
      half2_t uo = __builtin_bit_cast(half2_t, up);
      const float h1 = tanhf((float)uo.x);
      const float h2 = tanhf((float)uo.y);
      hb32[64 * s + (tid >> 3)] = pack_f16x2(h1, h2);
      ((unsigned int*)hs)[(size_t)(b * 256 + t) * 256 + 64 * s + (tid >> 3)] =
          (unsigned int)f32_to_bf16(h1) | ((unsigned int)f32_to_bf16(h2) << 16);
    }
    __syncthreads();  // own-slice LDS update visible before next phase 1
  }
}

// ---------------------------------------------------------------------------
// Output GEMM: C[16384,4096] = A[16384,512](bf16) @ WoT^T + Bo.  m97 structure
// + bijective XCD-chunked block swizzle (T1; 4096 % 8 == 0) so consecutive
// same-XCD blocks share the A panel in their XCD's L2.
// ---------------------------------------------------------------------------
__global__ __launch_bounds__(256) void gemm_out(const unsigned short* __restrict__ A,
                                                const unsigned short* __restrict__ Bt,
                                                const float* __restrict__ Bo,
                                                float* __restrict__ C) {
  __shared__ alignas(16) unsigned short As[128 * 32];
  __shared__ alignas(16) unsigned short Bs[128 * 32];
  const int tid = threadIdx.x;
  const int lane = tid & 63, wid = tid >> 6;
  const int swz = (blockIdx.x & 7) * 512 + (blockIdx.x >> 3);  // XCD-chunked
  const int bn = swz & 31, bm = swz >> 5;
  const int wr = wid >> 1, wc = wid & 1;

  f32x4 acc[4][4] = {};

  const unsigned short* Ag = A + (size_t)(bm * 128 + (tid >> 2)) * 512 + (tid & 3) * 8;
  const unsigned short* Bg = Bt + (size_t)(bn * 128 + (tid >> 2)) * 512 + (tid & 3) * 8;
  char* AsW = (char*)As + wid * 1024;
  char* BsW = (char*)Bs + wid * 1024;

  const int laneRow = lane & 15;
  const int k0 = (lane >> 4) * 8;

  for (int kt = 0; kt < 16; ++kt) {
    __syncthreads();
    const unsigned short* a0 = Ag + kt * 32;
    const unsigned short* b0 = Bg + kt * 32;
    glds16(a0,            AsW);
    glds16(a0 + 64 * 512, AsW + 4096);
    glds16(b0,            BsW);
    glds16(b0 + 64 * 512, BsW + 4096);
    __syncthreads();

    short8 af[4], bf[4];
#pragma unroll
    for (int f = 0; f < 4; ++f)
      af[f] = *(const short8*)&As[(wr * 64 + f * 16 + laneRow) * 32 + k0];
#pragma unroll
    for (int f = 0; f < 4; ++f)
      bf[f] = *(const short8*)&Bs[(wc * 64 + f * 16 + laneRow) * 32 + k0];
#pragma unroll
    for (int fm = 0; fm < 4; ++fm)
#pragma unroll
      for (int fn = 0; fn < 4; ++fn)
        acc[fm][fn] = __builtin_amdgcn_mfma_f32_16x16x32_bf16(af[fm], bf[fn], acc[fm][fn], 0, 0, 0);
  }

  const int mg0 = bm * 128 + wr * 64, ng0 = bn * 128 + wc * 64;
#pragma unroll
  for (int fn = 0; fn < 4; ++fn) {
    const int col = ng0 + fn * 16 + laneRow;
    const float bo = Bo[col];
#pragma unroll
    for (int fm = 0; fm < 4; ++fm) {
      const int row0 = mg0 + fm * 16 + (lane >> 4) * 4;
#pragma unroll
      for (int r = 0; r < 4; ++r)
        C[(size_t)(row0 + r) * 4096 + col] = acc[fm][fn][r] + bo;
    }
  }
}

// ---------------------------------------------------------------------------
extern "C" void kernel_launch(void* const* d_in, const int* in_sizes, int n_in,
                              void* d_out, int out_size, void* d_ws, size_t ws_size,
                              hipStream_t stream) {
  (void)in_sizes; (void)n_in; (void)out_size; (void)ws_size;
  const int* x = (const int*)d_in[0];
  const float* Wxh = (const float*)d_in[1];
  const float* Whh = (const float*)d_in[2];
  const float* bh = (const float*)d_in[3];
  const float* Wo = (const float*)d_in[4];
  const float* Bo = (const float*)d_in[5];
  float* out = (float*)d_out;

  // workspace map (bytes):
  //   WhhB   @ 0         512 KB
  //   WoT    @ 524288    4 MB
  //   hs     @ 4718592   16 MB
  //   hG64   @ 21495808  256 KB   (2 x 64 x 256 tagged u64)
  unsigned int* WhhB = (unsigned int*)d_ws;
  unsigned short* WoT = (unsigned short*)((char*)d_ws + 524288);
  unsigned short* hs = (unsigned short*)((char*)d_ws + 4718592);
  unsigned long long* hG64 = (unsigned long long*)((char*)d_ws + 21495808);

  hipLaunchKernelGGL(pack_whhB, dim3(512), dim3(256), 0, stream, Whh, WhhB, hG64);
  hipLaunchKernelGGL(transpose_wo, dim3(64, 8), dim3(256), 0, stream, Wo, WoT);
  hipLaunchKernelGGL(rnn_scanH, dim3(256), dim3(512), 0, stream, x, Wxh, WhhB, bh,
                     hs, hG64);
  hipLaunchKernelGGL(gemm_out, dim3(4096), dim3(256), 0, stream, hs, WoT, Bo, out);
}

// Round 23
// 477.094 us; speedup vs baseline: 1.2698x; 1.2698x over previous
//
#include <hip/hip_runtime.h>

// Problem constants: B=64, T=256, V=4096, H=512
// Inputs: x[B*T] i32, Wxh[V,H] f32, Whh[H,H] f32, bh[H] f32, Wo[H,V] f32, Bo[V] f32
// Output: out[B,T,V] f32 = (scan hs) @ Wo + Bo

typedef __fp16 half2_t __attribute__((ext_vector_type(2)));
typedef __attribute__((ext_vector_type(8))) short short8;   // 8 bf16 (MFMA A/B frag)
typedef __attribute__((ext_vector_type(4))) float f32x4;    // MFMA C/D frag

__device__ __forceinline__ unsigned short f32_to_bf16(float f) {
  unsigned int u = __builtin_bit_cast(unsigned int, f);
  u = (u + 0x7FFFu + ((u >> 16) & 1u)) >> 16;  // RNE
  return (unsigned short)u;
}

__device__ __forceinline__ unsigned int pack_f16x2(float a, float b) {
  half2_t h = __builtin_amdgcn_cvt_pkrtz(a, b);
  return __builtin_bit_cast(unsigned int, h);
}

__device__ __forceinline__ float fdot2_(unsigned int w, unsigned int h, float acc) {
  return __builtin_amdgcn_fdot2(__builtin_bit_cast(half2_t, w),
                                __builtin_bit_cast(half2_t, h), acc, false);
}

__device__ __forceinline__ void glds16(const void* g, void* lds) {
  __builtin_amdgcn_global_load_lds(
      (const __attribute__((address_space(1))) unsigned int*)g,
      (__attribute__((address_space(3))) unsigned int*)lds, 16, 0, 0);
}

// ---------------------------------------------------------------------------
// Prep 1: Whh -> WhhQ, q-interleaved per-slice LDS image matched to the scan's
// (c = tid>>2, q = tid&3) lane mapping. uint4 index
//   U = ((s*16 + g)*128 + c)*4 + q   (g = chunk-group 0..15, kc = 4g+q)
// holds f16 pairs p = 16g + 4q + e (e=0..3; h elems 2p,2p+1) of column
// j = s*128 + c. In-scan, lane l = c_low*4+q of a wave reads
// wlds[(g*128 + c)*4 + q] -> byte addr = g*8192 + c*64 + q*16 = base + l*16:
// CONTIGUOUS 1024 B per wave, conflict-free (R22's 1e8 bank conflicts came
// from the old layout's 2048B q-stride). Zeroes hG64 tags every launch.
// ---------------------------------------------------------------------------
__global__ __launch_bounds__(256) void pack_whhQ(const float* __restrict__ Whh,
                                                 unsigned int* __restrict__ WhhQ,
                                                 unsigned long long* __restrict__ hG64) {
  int idx = blockIdx.x * 256 + threadIdx.x;  // 131072 u32 total
  int e = idx & 3;
  int U = idx >> 2;
  int q = U & 3;
  int c = (U >> 2) & 127;
  int g = (U >> 9) & 15;
  int s = U >> 13;
  int p = 16 * g + 4 * q + e;   // f16-pair index 0..255
  int j = s * 128 + c;          // column
  float f0 = Whh[(2 * p) * 512 + j];
  float f1 = Whh[(2 * p + 1) * 512 + j];
  WhhQ[idx] = pack_f16x2(f0, f1);
  if (idx < 32768) hG64[idx] = 0ull;  // tag 0 != any target t>=1
}

// ---------------------------------------------------------------------------
// Prep 2: Wo [h][v] f32 -> WoT [v][h] bf16
// ---------------------------------------------------------------------------
__global__ __launch_bounds__(256) void transpose_wo(const float* __restrict__ Wo,
                                                    unsigned short* __restrict__ WoT) {
  __shared__ float tile[64][65];
  const int tv = blockIdx.x;   // 0..63  (V/64)
  const int th = blockIdx.y;   // 0..7   (H/64)
  const int tid = threadIdx.x;
  const int c = tid & 63, r4 = tid >> 6;
#pragma unroll
  for (int p = 0; p < 16; ++p) {
    int hl = p * 4 + r4;
    tile[hl][c] = Wo[(size_t)(th * 64 + hl) * 4096 + tv * 64 + c];
  }
  __syncthreads();
#pragma unroll
  for (int p = 0; p < 16; ++p) {
    int vl = p * 4 + r4;
    WoT[(size_t)(tv * 64 + vl) * 512 + th * 64 + c] = f32_to_bf16(tile[c][vl]);
  }
}

// ---------------------------------------------------------------------------
// Recurrence vI: R22's shfl-reduce structure + conflict-free q-interleaved
// weight layout (the R22 regression was pure LDS bank conflict, 1.0e8 counted
// = ~1530 cyc/step). Thread (c = tid>>2, q = tid&3): column j = 128s+c,
// chunks kc = 4g+q for g = 0..15. Step: phase1 (own-quarter groups g =
// 4s..4s+3, locally-produced h) || poll -> barrier -> phase2 (12 remote
// groups) -> shfl_xor k-reduce (q in lane bits) -> tagged pre-tanh store ->
// barrier. 2 barriers/step, no pbuf. Sync protocol byte-identical to
// R15/R17/R21 (tagged u64, parity buffers, 192 pollers, tags zeroed).
// ---------------------------------------------------------------------------
#define DOTG(g_, A) do { \
  const uint4 w_ = wlds[((g_) * 128 + c) * 4 + q]; \
  const uint4 h_ = hbuf[4 * (g_) + q]; \
  A = fdot2_(w_.x, h_.x, A); A = fdot2_(w_.y, h_.y, A); \
  A = fdot2_(w_.z, h_.z, A); A = fdot2_(w_.w, h_.w, A); } while (0)

__global__ __launch_bounds__(512) void rnn_scanI(const int* __restrict__ x,
                                                 const float* __restrict__ Wxh,
                                                 const unsigned int* __restrict__ WhhQ,
                                                 const float* __restrict__ bh,
                                                 unsigned short* __restrict__ hs,
                                                 unsigned long long* hG64) {
  __shared__ uint4 wlds[8192];   // 128 KB: this block's full weight slice
  __shared__ uint4 hbuf[64];     // 512 h values as f16 pairs
  __shared__ int toks[256];
  const int bid = blockIdx.x;
  const int s = bid & 3;         // column-slice (proven mapping)
  const int b = bid >> 2;        // batch
  const int tid = threadIdx.x;
  const int c = tid >> 2;        // column within slice (0..127)
  const int q = tid & 3;         // k-phase (lane bits 0-1)
  const uint4* W4 = (const uint4*)WhhQ;

  // stage this block's 128 KB weight slice (coalesced, 16 rounds; pack
  // kernel already produced the in-LDS layout, so staging is linear)
#pragma unroll
  for (int it = 0; it < 16; ++it) {
    int L = it * 512 + tid;
    wlds[L] = W4[s * 8192 + L];
  }
  if (tid < 64) hbuf[tid] = make_uint4(0u, 0u, 0u, 0u);  // h0 = 0
  if (tid < 256) toks[tid] = x[b * 256 + tid];
  __syncthreads();

  unsigned int* hb32 = (unsigned int*)hbuf;      // [256] u32 view of h pairs
  const float bhj = bh[s * 128 + c];
  // poll-slot for tid<192: word index within 256, skipping own slice
  const int rslot = (tid < s * 64) ? tid : tid + 64;

  for (int t = 0; t < 256; ++t) {
    const int tok = toks[t];
    // xv prefetch (16 distinct addrs/wave, broadcast within 4-lane groups)
    const float xv = Wxh[(size_t)tok * 512 + s * 128 + c];

    float a0 = 0.f, a1 = 0.f, a2 = 0.f, a3 = 0.f;
    // phase 1: own-quarter groups (h written locally last step) --
    // overlaps the siblings' store->LLC-visibility window
    DOTG(4 * s + 0, a0); DOTG(4 * s + 1, a1);
    DOTG(4 * s + 2, a2); DOTG(4 * s + 3, a3);

    if (t > 0 && tid < 192) {
      // pull 192 remote u-pairs: spin on own tagged word, tanh on receipt
      const unsigned long long* src =
          hG64 + (((size_t)(t & 1)) << 14) + b * 256 + rslot;
      unsigned long long v;
      do {
        v = __hip_atomic_load(src, __ATOMIC_RELAXED, __HIP_MEMORY_SCOPE_AGENT);
      } while ((unsigned)(v >> 32) != (unsigned)t);
      half2_t up = __builtin_bit_cast(half2_t, (unsigned)v);
      hb32[rslot] = pack_f16x2(tanhf((float)up.x), tanhf((float)up.y));
    }
    __syncthreads();  // remote h in LDS for all waves

    // phase 2: the three remote quarters (4 groups each)
    {
      const int g1 = ((s + 1) & 3) * 4;
      DOTG(g1 + 0, a0); DOTG(g1 + 1, a1); DOTG(g1 + 2, a2); DOTG(g1 + 3, a3);
      const int g2 = ((s + 2) & 3) * 4;
      DOTG(g2 + 0, a0); DOTG(g2 + 1, a1); DOTG(g2 + 2, a2); DOTG(g2 + 3, a3);
      const int g3 = ((s + 3) & 3) * 4;
      DOTG(g3 + 0, a0); DOTG(g3 + 1, a1); DOTG(g3 + 2, a2); DOTG(g3 + 3, a3);
    }
    // cross-lane k-reduce: q lives in lane bits 0-1
    float asum = (a0 + a1) + (a2 + a3);
    asum += __shfl_xor(asum, 1);
    asum += __shfl_xor(asum, 2);

    const float u1 = xv + asum + bhj;          // valid on all 4 q-lanes
    const float u2 = __shfl_down(u1, 4);       // col c+1's u (even-c lanes)
    if ((tid & 7) == 0) {                      // one lane per even column
      const unsigned int up = pack_f16x2(u1, u2);
      __hip_atomic_store(
          hG64 + (((size_t)((t + 1) & 1)) << 14) + b * 256 + 64 * s + (tid >> 3),
          ((unsigned long long)(unsigned)(t + 1) << 32) | up,
          __ATOMIC_RELAXED, __HIP_MEMORY_SCOPE_AGENT);
      // own h from the SAME rounded u (bit-consistent with readers)
      half2_t uo = __builtin_bit_cast(half2_t, up);
      const float h1 = tanhf((float)uo.x);
      const float h2 = tanhf((float)uo.y);
      hb32[64 * s + (tid >> 3)] = pack_f16x2(h1, h2);
      ((unsigned int*)hs)[(size_t)(b * 256 + t) * 256 + 64 * s + (tid >> 3)] =
          (unsigned int)f32_to_bf16(h1) | ((unsigned int)f32_to_bf16(h2) << 16);
    }
    __syncthreads();  // own-slice LDS update visible before next phase 1
  }
}

// ---------------------------------------------------------------------------
// Output GEMM: C[16384,4096] = A[16384,512](bf16) @ WoT^T + Bo.  m97 structure
// (R22's XCD swizzle reverted: measured +5 us).
// ---------------------------------------------------------------------------
__global__ __launch_bounds__(256) void gemm_out(const unsigned short* __restrict__ A,
                                                const unsigned short* __restrict__ Bt,
                                                const float* __restrict__ Bo,
                                                float* __restrict__ C) {
  __shared__ alignas(16) unsigned short As[128 * 32];
  __shared__ alignas(16) unsigned short Bs[128 * 32];
  const int tid = threadIdx.x;
  const int lane = tid & 63, wid = tid >> 6;
  const int bn = blockIdx.x & 31, bm = blockIdx.x >> 5;
  const int wr = wid >> 1, wc = wid & 1;

  f32x4 acc[4][4] = {};

  const unsigned short* Ag = A + (size_t)(bm * 128 + (tid >> 2)) * 512 + (tid & 3) * 8;
  const unsigned short* Bg = Bt + (size_t)(bn * 128 + (tid >> 2)) * 512 + (tid & 3) * 8;
  char* AsW = (char*)As + wid * 1024;
  char* BsW = (char*)Bs + wid * 1024;

  const int laneRow = lane & 15;
  const int k0 = (lane >> 4) * 8;

  for (int kt = 0; kt < 16; ++kt) {
    __syncthreads();
    const unsigned short* a0 = Ag + kt * 32;
    const unsigned short* b0 = Bg + kt * 32;
    glds16(a0,            AsW);
    glds16(a0 + 64 * 512, AsW + 4096);
    glds16(b0,            BsW);
    glds16(b0 + 64 * 512, BsW + 4096);
    __syncthreads();

    short8 af[4], bf[4];
#pragma unroll
    for (int f = 0; f < 4; ++f)
      af[f] = *(const short8*)&As[(wr * 64 + f * 16 + laneRow) * 32 + k0];
#pragma unroll
    for (int f = 0; f < 4; ++f)
      bf[f] = *(const short8*)&Bs[(wc * 64 + f * 16 + laneRow) * 32 + k0];
#pragma unroll
    for (int fm = 0; fm < 4; ++fm)
#pragma unroll
      for (int fn = 0; fn < 4; ++fn)
        acc[fm][fn] = __builtin_amdgcn_mfma_f32_16x16x32_bf16(af[fm], bf[fn], acc[fm][fn], 0, 0, 0);
  }

  const int mg0 = bm * 128 + wr * 64, ng0 = bn * 128 + wc * 64;
#pragma unroll
  for (int fn = 0; fn < 4; ++fn) {
    const int col = ng0 + fn * 16 + laneRow;
    const float bo = Bo[col];
#pragma unroll
    for (int fm = 0; fm < 4; ++fm) {
      const int row0 = mg0 + fm * 16 + (lane >> 4) * 4;
#pragma unroll
      for (int r = 0; r < 4; ++r)
        C[(size_t)(row0 + r) * 4096 + col] = acc[fm][fn][r] + bo;
    }
  }
}

// ---------------------------------------------------------------------------
extern "C" void kernel_launch(void* const* d_in, const int* in_sizes, int n_in,
                              void* d_out, int out_size, void* d_ws, size_t ws_size,
                              hipStream_t stream) {
  (void)in_sizes; (void)n_in; (void)out_size; (void)ws_size;
  const int* x = (const int*)d_in[0];
  const float* Wxh = (const float*)d_in[1];
  const float* Whh = (const float*)d_in[2];
  const float* bh = (const float*)d_in[3];
  const float* Wo = (const float*)d_in[4];
  const float* Bo = (const float*)d_in[5];
  float* out = (float*)d_out;

  // workspace map (bytes):
  //   WhhQ   @ 0         512 KB
  //   WoT    @ 524288    4 MB
  //   hs     @ 4718592   16 MB
  //   hG64   @ 21495808  256 KB   (2 x 64 x 256 tagged u64)
  unsigned int* WhhQ = (unsigned int*)d_ws;
  unsigned short* WoT = (unsigned short*)((char*)d_ws + 524288);
  unsigned short* hs = (unsigned short*)((char*)d_ws + 4718592);
  unsigned long long* hG64 = (unsigned long long*)((char*)d_ws + 21495808);

  hipLaunchKernelGGL(pack_whhQ, dim3(512), dim3(256), 0, stream, Whh, WhhQ, hG64);
  hipLaunchKernelGGL(transpose_wo, dim3(64, 8), dim3(256), 0, stream, Wo, WoT);
  hipLaunchKernelGGL(rnn_scanI, dim3(256), dim3(512), 0, stream, x, Wxh, WhhQ, bh,
                     hs, hG64);
  hipLaunchKernelGGL(gemm_out, dim3(4096), dim3(256), 0, stream, hs, WoT, Bo, out);
}